// Round 5
// baseline (239.909 us; speedup 1.0000x reference)
//
#include <hip/hip_runtime.h>
#include <hip/hip_bf16.h>

#define IN_F 8192
#define OUT_F 8192
#define SEQ 64
#define LORA_R 16
#define KH 4096            // K per split-K half

typedef __attribute__((ext_vector_type(4))) float f32x4;
typedef __attribute__((ext_vector_type(4))) int i32x4;
typedef __attribute__((ext_vector_type(8))) unsigned short u16x8;
typedef _Float16 f16x2 __attribute__((ext_vector_type(2)));
typedef _Float16 f16x8 __attribute__((ext_vector_type(8)));

// ---- cast x -> fp16 into ws (one shot, fully parallel) ----
__global__ __launch_bounds__(256) void k_cast(const float* __restrict__ x,
                                              unsigned short* __restrict__ xb) {
    const int i = (blockIdx.x * 256 + threadIdx.x) * 8;
    f32x4 v0 = *(const f32x4*)(x + i);
    f32x4 v1 = *(const f32x4*)(x + i + 4);
    u16x8 h;
    h[0] = __builtin_bit_cast(unsigned short, (_Float16)v0.x);
    h[1] = __builtin_bit_cast(unsigned short, (_Float16)v0.y);
    h[2] = __builtin_bit_cast(unsigned short, (_Float16)v0.z);
    h[3] = __builtin_bit_cast(unsigned short, (_Float16)v0.w);
    h[4] = __builtin_bit_cast(unsigned short, (_Float16)v1.x);
    h[5] = __builtin_bit_cast(unsigned short, (_Float16)v1.y);
    h[6] = __builtin_bit_cast(unsigned short, (_Float16)v1.z);
    h[7] = __builtin_bit_cast(unsigned short, (_Float16)v1.w);
    *(u16x8*)(xb + i) = h;
}

// ---- t = x @ A^T : one block per s-row, atomic-free (LDS reduce) ----
__global__ __launch_bounds__(512) void k_t(const float* __restrict__ x,
                                           const float* __restrict__ A,
                                           float* __restrict__ t) {
    __shared__ float p[LORA_R][33];
    const int s = blockIdx.x;
    const int r = threadIdx.x & 15, seg = threadIdx.x >> 4;   // seg 0..31, 256 cols each
    const float* xr = x + s * IN_F + seg * 256;
    const float* ar = A + r * IN_F + seg * 256;
    float acc = 0.f;
    #pragma unroll 8
    for (int j = 0; j < 64; ++j) {
        f32x4 xv = *(const f32x4*)(xr + j * 4);
        f32x4 av = *(const f32x4*)(ar + j * 4);
        acc = fmaf(xv.x, av.x, acc);
        acc = fmaf(xv.y, av.y, acc);
        acc = fmaf(xv.z, av.z, acc);
        acc = fmaf(xv.w, av.w, acc);
    }
    p[r][seg] = acc;
    __syncthreads();
    if (threadIdx.x < LORA_R) {
        float v = 0.f;
        #pragma unroll
        for (int g = 0; g < 32; ++g) v += p[threadIdx.x][g];
        t[s * LORA_R + threadIdx.x] = v;
    }
}

// ---- main: 512 blocks = 256 n-tiles(32) x 2 K-halves; 512 thr = 8 waves ----
// Pipeline: distance-2 register prefetch, double-buffered LDS, ONE barrier/iter.
// LDS (60928 B): xs [2][64*136] f16 | wt [2][32*68] int | scs [32*68] f32
__global__ __launch_bounds__(512, 4) void k_main(
    const int* __restrict__ packed, const float* __restrict__ scales,
    const unsigned short* __restrict__ xb, const float* __restrict__ t,
    const float* __restrict__ B, float* __restrict__ out) {
    __shared__ char lds[60928];
    _Float16* xs = (_Float16*)lds;
    int* wt = (int*)(lds + 34816);
    float* scs = (float*)(lds + 52224);
    float* accs = (float*)lds;

    const int tid = threadIdx.x;
    const int n0 = (blockIdx.x >> 1) * 32;
    const int kh = blockIdx.x & 1;
    const int w = tid >> 6, lane = tid & 63;
    const int nh = w >> 2, wkk = w & 3;
    const int q = lane >> 4, c16 = lane & 15;

    {   // scales for 32 rows, this K-half, staged once
        int row = tid >> 4, g = tid & 15;
        f32x4 v = *(const f32x4*)(scales + (n0 + row) * (IN_F / 64) + kh * 64 + g * 4);
        *(f32x4*)(scs + row * 68 + g * 4) = v;
    }

    const int xrow = tid >> 3, xseg = tid & 7;
    const int wrow = tid >> 4, wg = tid & 15;
    const unsigned short* xsrc = xb + xrow * IN_F + kh * KH + xseg * 16;
    const int* wsrc = packed + (long)(n0 + wrow) * (IN_F / 2) + kh * (KH / 2) + wg * 4;
    _Float16* xdst0 = xs + xrow * 136 + xseg * 16;
    int* wdst0 = wt + wrow * 68 + wg * 4;

    f32x4 acc[4];
    #pragma unroll
    for (int mt = 0; mt < 4; ++mt) acc[mt] = (f32x4){0.f, 0.f, 0.f, 0.f};

    const f16x2 c1032 = {(_Float16)1032.0f, (_Float16)1032.0f};

    auto compute = [&](int buf, int kt) {
        i32x4 pv = *(const i32x4*)(wt + buf * (32 * 68) + (nh * 16 + c16) * 68 + wkk * 16 + q * 4);
        float scf = scs[(nh * 16 + c16) * 68 + kt * 2 + (wkk >> 1)];
        _Float16 sch = (_Float16)scf;
        f16x2 sc2 = {sch, sch};
        f16x8 bf;
        #pragma unroll
        for (int m = 0; m < 4; ++m) {
            unsigned u = ((((unsigned)pv[m] << 12) | (unsigned)pv[m]) & 0x000F000Fu) | 0x64006400u;
            f16x2 h = __builtin_bit_cast(f16x2, u);
            h = (h - c1032) * sc2;          // exact (q-8)*scale
            bf[2 * m] = h.x;
            bf[2 * m + 1] = h.y;
        }
        const _Float16* xbase = xs + buf * (64 * 136) + wkk * 32 + q * 8;
        #pragma unroll
        for (int mt = 0; mt < 4; ++mt) {
            f16x8 af = *(const f16x8*)(xbase + (mt * 16 + c16) * 136);
            acc[mt] = __builtin_amdgcn_mfma_f32_16x16x32_f16(af, bf, acc[mt], 0, 0, 0);
        }
    };

    // prologue: iter0 -> buf0; issue iter1 loads (in flight across barrier)
    u16x8 a0 = *(const u16x8*)(xsrc);
    u16x8 b0 = *(const u16x8*)(xsrc + 8);
    i32x4 w0 = *(const i32x4*)(wsrc);
    *(u16x8*)xdst0 = a0;
    *(u16x8*)(xdst0 + 8) = b0;
    *(i32x4*)wdst0 = w0;
    u16x8 a1 = *(const u16x8*)(xsrc + 128);
    u16x8 b1 = *(const u16x8*)(xsrc + 128 + 8);
    i32x4 w1 = *(const i32x4*)(wsrc + 64);
    __syncthreads();

    for (int kt = 0; kt < 32; kt += 2) {
        // ---- even iter kt: compute buf0 ----
        if (kt + 2 < 32) {              // issue loads for kt+2 into set0
            a0 = *(const u16x8*)(xsrc + (kt + 2) * 128);
            b0 = *(const u16x8*)(xsrc + (kt + 2) * 128 + 8);
            w0 = *(const i32x4*)(wsrc + (kt + 2) * 64);
        }
        compute(0, kt);
        // store set1 (kt+1 data, issued a full iter ago) into buf1
        *(u16x8*)(xs + 64 * 136 + xrow * 136 + xseg * 16) = a1;
        *(u16x8*)(xs + 64 * 136 + xrow * 136 + xseg * 16 + 8) = b1;
        *(i32x4*)(wt + 32 * 68 + wrow * 68 + wg * 4) = w1;
        __syncthreads();
        // ---- odd iter kt+1: compute buf1 ----
        if (kt + 3 < 32) {              // issue loads for kt+3 into set1
            a1 = *(const u16x8*)(xsrc + (kt + 3) * 128);
            b1 = *(const u16x8*)(xsrc + (kt + 3) * 128 + 8);
            w1 = *(const i32x4*)(wsrc + (kt + 3) * 64);
        }
        compute(1, kt + 1);
        if (kt + 2 < 32) {              // store set0 (kt+2 data) into buf0
            *(u16x8*)xdst0 = a0;
            *(u16x8*)(xdst0 + 8) = b0;
            *(i32x4*)wdst0 = w0;
            __syncthreads();
        }
    }
    __syncthreads();   // protect xs before aliasing as accs

    // ---- epilogue: cross-wave reduce + LoRA (kh0 only) + atomic out ----
    float* myacc = accs + w * (64 * 17);
    #pragma unroll
    for (int mt = 0; mt < 4; ++mt)
        #pragma unroll
        for (int r = 0; r < 4; ++r)
            myacc[(mt * 16 + q * 4 + r) * 17 + c16] = acc[mt][r];
    __syncthreads();

    #pragma unroll
    for (int j = 0; j < 4; ++j) {
        int p = tid + j * 512;                    // s in 0..63, c in 0..31
        int s = p >> 5, c = p & 31;
        const float* ab = accs + (c >> 4) * 4 * (64 * 17) + s * 17 + (c & 15);
        float v = ab[0] + ab[64 * 17] + ab[2 * 64 * 17] + ab[3 * 64 * 17];
        if (kh == 0) {
            const float* tp = t + s * LORA_R;
            const float* bp = B + (n0 + c) * LORA_R;
            float lr = 0.f;
            #pragma unroll
            for (int r = 0; r < LORA_R; ++r) lr = fmaf(tp[r], bp[r], lr);
            v += 2.0f * lr;
        }
        unsafeAtomicAdd(&out[s * OUT_F + n0 + c], v);
    }
}

extern "C" void kernel_launch(void* const* d_in, const int* in_sizes, int n_in,
                              void* d_out, int out_size, void* d_ws, size_t ws_size,
                              hipStream_t stream) {
    const float* x      = (const float*)d_in[0];
    const int* packed   = (const int*)d_in[1];
    const float* scales = (const float*)d_in[2];
    const float* lora_A = (const float*)d_in[3];
    const float* lora_B = (const float*)d_in[4];
    float* out = (float*)d_out;

    unsigned short* xb = (unsigned short*)d_ws;                 // 1 MiB fp16 x
    float* t = (float*)((char*)d_ws + (size_t)SEQ * IN_F * 2);  // 4 KiB

    hipMemsetAsync(out, 0, (size_t)SEQ * OUT_F * sizeof(float), stream);
    k_cast<<<SEQ * IN_F / (256 * 8), 256, 0, stream>>>(x, xb);
    k_t<<<SEQ, 512, 0, stream>>>(x, lora_A, t);
    k_main<<<512, 512, 0, stream>>>(packed, scales, xb, t, lora_B, out);
}

// Round 6
// 234.946 us; speedup vs baseline: 1.0211x; 1.0211x over previous
//
#include <hip/hip_runtime.h>
#include <hip/hip_bf16.h>

#define IN_F 8192
#define OUT_F 8192
#define SEQ 64
#define LORA_R 16
#define KH 4096            // K per split-K half

typedef __attribute__((ext_vector_type(4))) float f32x4;
typedef __attribute__((ext_vector_type(4))) int i32x4;
typedef __attribute__((ext_vector_type(8))) unsigned short u16x8;
typedef __attribute__((ext_vector_type(4))) unsigned short u16x4;
typedef _Float16 f16x2 __attribute__((ext_vector_type(2)));
typedef _Float16 f16x8 __attribute__((ext_vector_type(8)));

// ---- fused prep: zero out, cast x->fp16 into ws, and (blocks 0..63) t = x@A^T ----
// grid 256 x 512 thr. Each thread handles 4 consecutive floats of x/out.
__global__ __launch_bounds__(512) void k_prep(
    const float* __restrict__ x, const float* __restrict__ A,
    unsigned short* __restrict__ xb, float* __restrict__ t,
    float* __restrict__ out) {
    const int tid = threadIdx.x;
    const int gi = blockIdx.x * 512 + tid;        // 131072 threads x 4 elems

    f32x4 v = *(const f32x4*)(x + gi * 4);
    u16x4 h;
    h[0] = __builtin_bit_cast(unsigned short, (_Float16)v.x);
    h[1] = __builtin_bit_cast(unsigned short, (_Float16)v.y);
    h[2] = __builtin_bit_cast(unsigned short, (_Float16)v.z);
    h[3] = __builtin_bit_cast(unsigned short, (_Float16)v.w);
    *(u16x4*)(xb + gi * 4) = h;
    *(f32x4*)(out + gi * 4) = (f32x4){0.f, 0.f, 0.f, 0.f};

    if (blockIdx.x < SEQ) {   // t-row for s = blockIdx.x
        __shared__ float p[LORA_R][33];
        const int s = blockIdx.x;
        const int r = tid & 15, seg = tid >> 4;   // 32 segments x 256 cols
        const float* xr = x + s * IN_F + seg * 256;
        const float* ar = A + r * IN_F + seg * 256;
        float acc = 0.f;
        #pragma unroll 8
        for (int j = 0; j < 64; ++j) {
            f32x4 xv = *(const f32x4*)(xr + j * 4);
            f32x4 av = *(const f32x4*)(ar + j * 4);
            acc = fmaf(xv.x, av.x, acc);
            acc = fmaf(xv.y, av.y, acc);
            acc = fmaf(xv.z, av.z, acc);
            acc = fmaf(xv.w, av.w, acc);
        }
        p[r][seg] = acc;
        __syncthreads();
        if (tid < LORA_R) {
            float sum = 0.f;
            #pragma unroll
            for (int g = 0; g < 32; ++g) sum += p[tid][g];
            t[s * LORA_R + tid] = sum;
        }
    }
}

// ---- main: 512 blocks = 256 n-tiles(32) x 2 K-halves; 512 thr = 8 waves ----
// W loads are NON-TEMPORAL (stream-once, don't evict xb from L2).
// LDS (60928 B): xs [2][64*136] f16 | wt [2][32*68] int | scs [32*68] f32
__global__ __launch_bounds__(512, 4) void k_main(
    const int* __restrict__ packed, const float* __restrict__ scales,
    const unsigned short* __restrict__ xb, const float* __restrict__ t,
    const float* __restrict__ B, float* __restrict__ out) {
    __shared__ char lds[60928];
    _Float16* xs = (_Float16*)lds;
    int* wt = (int*)(lds + 34816);
    float* scs = (float*)(lds + 52224);
    float* accs = (float*)lds;

    const int tid = threadIdx.x;
    const int n0 = (blockIdx.x >> 1) * 32;
    const int kh = blockIdx.x & 1;
    const int w = tid >> 6, lane = tid & 63;
    const int nh = w >> 2, wkk = w & 3;
    const int q = lane >> 4, c16 = lane & 15;

    {   // scales for 32 rows, this K-half, staged once
        int row = tid >> 4, g = tid & 15;
        f32x4 v = *(const f32x4*)(scales + (n0 + row) * (IN_F / 64) + kh * 64 + g * 4);
        *(f32x4*)(scs + row * 68 + g * 4) = v;
    }

    const int xrow = tid >> 3, xseg = tid & 7;
    const int wrow = tid >> 4, wg = tid & 15;
    const unsigned short* xsrc = xb + xrow * IN_F + kh * KH + xseg * 16;
    const int* wsrc = packed + (long)(n0 + wrow) * (IN_F / 2) + kh * (KH / 2) + wg * 4;
    _Float16* xdst0 = xs + xrow * 136 + xseg * 16;
    int* wdst0 = wt + wrow * 68 + wg * 4;

    f32x4 acc[4];
    #pragma unroll
    for (int mt = 0; mt < 4; ++mt) acc[mt] = (f32x4){0.f, 0.f, 0.f, 0.f};

    const f16x2 c1032 = {(_Float16)1032.0f, (_Float16)1032.0f};

    // prologue: stage iter 0
    {
        u16x8 a0 = *(const u16x8*)(xsrc);
        u16x8 b0 = *(const u16x8*)(xsrc + 8);
        i32x4 w0 = __builtin_nontemporal_load((const i32x4*)wsrc);
        *(u16x8*)xdst0 = a0;
        *(u16x8*)(xdst0 + 8) = b0;
        *(i32x4*)wdst0 = w0;
    }
    __syncthreads();

    for (int kt = 0; kt < 32; ++kt) {
        const int cur = kt & 1;
        u16x8 ga, gb; i32x4 gw;
        if (kt < 31) {   // prefetch next BK chunk
            ga = *(const u16x8*)(xsrc + (kt + 1) * 128);
            gb = *(const u16x8*)(xsrc + (kt + 1) * 128 + 8);
            gw = __builtin_nontemporal_load((const i32x4*)(wsrc + (kt + 1) * 64));
        }
        // compute current buffer
        i32x4 pv = *(const i32x4*)(wt + cur * (32 * 68) + (nh * 16 + c16) * 68 + wkk * 16 + q * 4);
        float scf = scs[(nh * 16 + c16) * 68 + kt * 2 + (wkk >> 1)];
        _Float16 sch = (_Float16)scf;
        f16x2 sc2 = {sch, sch};
        f16x8 bf;
        #pragma unroll
        for (int m = 0; m < 4; ++m) {
            unsigned u = ((((unsigned)pv[m] << 12) | (unsigned)pv[m]) & 0x000F000Fu) | 0x64006400u;
            f16x2 hh = __builtin_bit_cast(f16x2, u);
            hh = (hh - c1032) * sc2;        // exact (q-8)*scale
            bf[2 * m] = hh.x;
            bf[2 * m + 1] = hh.y;
        }
        const _Float16* xbase = xs + cur * (64 * 136) + wkk * 32 + q * 8;
        #pragma unroll
        for (int mt = 0; mt < 4; ++mt) {
            f16x8 af = *(const f16x8*)(xbase + (mt * 16 + c16) * 136);
            acc[mt] = __builtin_amdgcn_mfma_f32_16x16x32_f16(af, bf, acc[mt], 0, 0, 0);
        }
        __syncthreads();
        if (kt < 31) {
            *(u16x8*)(xs + (1 - cur) * (64 * 136) + xrow * 136 + xseg * 16)     = ga;
            *(u16x8*)(xs + (1 - cur) * (64 * 136) + xrow * 136 + xseg * 16 + 8) = gb;
            *(i32x4*)(wt + (1 - cur) * (32 * 68) + wrow * 68 + wg * 4)          = gw;
        }
        __syncthreads();
    }

    // epilogue: cross-wave reduce + LoRA (kh0 only) + atomic out
    float* myacc = accs + w * (64 * 17);
    #pragma unroll
    for (int mt = 0; mt < 4; ++mt)
        #pragma unroll
        for (int r = 0; r < 4; ++r)
            myacc[(mt * 16 + q * 4 + r) * 17 + c16] = acc[mt][r];
    __syncthreads();

    #pragma unroll
    for (int j = 0; j < 4; ++j) {
        int p = tid + j * 512;                    // s in 0..63, c in 0..31
        int s = p >> 5, c = p & 31;
        const float* ab = accs + (c >> 4) * 4 * (64 * 17) + s * 17 + (c & 15);
        float v = ab[0] + ab[64 * 17] + ab[2 * 64 * 17] + ab[3 * 64 * 17];
        if (kh == 0) {
            const float* tp = t + s * LORA_R;
            const float* bp = B + (n0 + c) * LORA_R;
            float lr = 0.f;
            #pragma unroll
            for (int r = 0; r < LORA_R; ++r) lr = fmaf(tp[r], bp[r], lr);
            v += 2.0f * lr;
        }
        unsafeAtomicAdd(&out[s * OUT_F + n0 + c], v);
    }
}

extern "C" void kernel_launch(void* const* d_in, const int* in_sizes, int n_in,
                              void* d_out, int out_size, void* d_ws, size_t ws_size,
                              hipStream_t stream) {
    const float* x      = (const float*)d_in[0];
    const int* packed   = (const int*)d_in[1];
    const float* scales = (const float*)d_in[2];
    const float* lora_A = (const float*)d_in[3];
    const float* lora_B = (const float*)d_in[4];
    float* out = (float*)d_out;

    unsigned short* xb = (unsigned short*)d_ws;                 // 1 MiB fp16 x
    float* t = (float*)((char*)d_ws + (size_t)SEQ * IN_F * 2);  // 4 KiB

    k_prep<<<256, 512, 0, stream>>>(x, lora_A, xb, t, out);
    k_main<<<512, 512, 0, stream>>>(packed, scales, xb, t, lora_B, out);
}